// Round 13
// baseline (331.949 us; speedup 1.0000x reference)
//
#include <hip/hip_runtime.h>

#define CC 128          // channels
#define BSEG 16         // segments
#define EPSV 1e-5f
#define ROWS_PER_BLOCK 1024   // R13: 512 -> 1024 (halve blocks & atomics)
#define NORM_GRID 2048
#define TILE_F4 4096    // float4s per tile = 128 rows = 64 KB (TILE_F4 % 256 == 0)

// Native clang vector (valid for __builtin_nontemporal_store, unlike HIP float4).
typedef float v4f __attribute__((ext_vector_type(4)));

// first index i in [0,n) with a[i] >= v   (a sorted ascending)
__device__ __forceinline__ int lower_bound_dev(const int* __restrict__ a, int n, int v)
{
    int lo = 0, hi = n;
    while (lo < hi) {
        const int mid = (lo + hi) >> 1;
        if (a[mid] < v) lo = mid + 1; else hi = mid;
    }
    return lo;
}

// ---------------------------------------------------------------------------
// Kernel 1: per-segment per-channel sum / sumsq.
// R13 changes vs R10: ROWS_PER_BLOCK 1024 (977 blocks, 250K atomics) and a
// 4-deep independent-load inner loop (4 x dwordx4 in flight per thread).
// FORWARD traversal leaves the tail of x freshest in L3 for the reverse norm.
// ---------------------------------------------------------------------------
__global__ __launch_bounds__(256) void ms_stats(const float* __restrict__ x,
                                                const int* __restrict__ bidx,
                                                int n,
                                                float* __restrict__ sum,
                                                float* __restrict__ sumsq)
{
    const int r0 = blockIdx.x * ROWS_PER_BLOCK;
    if (r0 >= n) return;
    const int rend = min(r0 + ROWS_PER_BLOCK, n);
    const int tq = threadIdx.x & 31;   // channel quad 0..31
    const int tr = threadIdx.x >> 5;   // row lane 0..7

    const int seg_first = bidx[r0];
    const int seg_last  = bidx[rend - 1];

    v4f s = {0.f, 0.f, 0.f, 0.f};
    v4f q = {0.f, 0.f, 0.f, 0.f};

    if (seg_first == seg_last) {
        // Uniform block: 4 independent loads per iteration (rows r..r+24).
        const float* px = x + tq * 4;
        int r = r0 + tr;
        for (; r + 24 < rend; r += 32) {
            const v4f a0 = *reinterpret_cast<const v4f*>(px + (size_t)(r     ) * CC);
            const v4f a1 = *reinterpret_cast<const v4f*>(px + (size_t)(r +  8) * CC);
            const v4f a2 = *reinterpret_cast<const v4f*>(px + (size_t)(r + 16) * CC);
            const v4f a3 = *reinterpret_cast<const v4f*>(px + (size_t)(r + 24) * CC);
            s += a0; q += a0 * a0;
            s += a1; q += a1 * a1;
            s += a2; q += a2 * a2;
            s += a3; q += a3 * a3;
        }
        for (; r < rend; r += 8) {
            const v4f a = *reinterpret_cast<const v4f*>(px + (size_t)r * CC);
            s += a; q += a * a;
        }
        // LDS reduce of 8 row-lanes; layout [tr][slot][tq] is lane-consecutive.
        __shared__ float red[8][8][32];
        red[tr][0][tq] = s.x; red[tr][1][tq] = s.y; red[tr][2][tq] = s.z; red[tr][3][tq] = s.w;
        red[tr][4][tq] = q.x; red[tr][5][tq] = q.y; red[tr][6][tq] = q.z; red[tr][7][tq] = q.w;
        __syncthreads();
        const int j = threadIdx.x >> 5;   // slot 0..7 (0-3 sum, 4-7 sumsq)
        float acc = 0.f;
        #pragma unroll
        for (int k = 0; k < 8; ++k) acc += red[k][j][tq];
        const int ch = tq * 4 + (j & 3);
        atomicAdd(((j < 4) ? sum : sumsq) + seg_first * CC + ch, acc);
    } else {
        // Boundary block (rare): flush per-thread accumulators on segment change.
        int cur = -1;
        for (int r = r0 + tr; r < rend; r += 8) {
            const int seg = bidx[r];
            if (seg != cur) {
                if (cur >= 0) {
                    float* sd = sum   + cur * CC + tq * 4;
                    float* qd = sumsq + cur * CC + tq * 4;
                    atomicAdd(sd + 0, s.x); atomicAdd(sd + 1, s.y);
                    atomicAdd(sd + 2, s.z); atomicAdd(sd + 3, s.w);
                    atomicAdd(qd + 0, q.x); atomicAdd(qd + 1, q.y);
                    atomicAdd(qd + 2, q.z); atomicAdd(qd + 3, q.w);
                    s = (v4f){0.f, 0.f, 0.f, 0.f};
                    q = (v4f){0.f, 0.f, 0.f, 0.f};
                }
                cur = seg;
            }
            const v4f a = *reinterpret_cast<const v4f*>(x + (size_t)r * CC + tq * 4);
            s += a; q += a * a;
        }
        if (cur >= 0) {
            float* sd = sum   + cur * CC + tq * 4;
            float* qd = sumsq + cur * CC + tq * 4;
            atomicAdd(sd + 0, s.x); atomicAdd(sd + 1, s.y);
            atomicAdd(sd + 2, s.z); atomicAdd(sd + 3, s.w);
            atomicAdd(qd + 0, q.x); atomicAdd(qd + 1, q.y);
            atomicAdd(qd + 2, q.z); atomicAdd(qd + 3, q.w);
        }
    }
}

// ---------------------------------------------------------------------------
// Kernel 2: normalize — EXACTLY R10 (best known: 302 us).
// Block-tile reverse sweep (64KB tiles descending from the tail: L3 harvest,
// FETCH measured 257MB of 512), dense per-lane float4, NT stores (R11 showed
// removing NT costs +33us), uniform tiles hold scale/shift in 2 registers.
// ---------------------------------------------------------------------------
__global__ __launch_bounds__(256) void ms_norm(const float* __restrict__ x,
                                               const int* __restrict__ bidx,
                                               const float* __restrict__ sum,
                                               const float* __restrict__ sumsq,
                                               const float* __restrict__ w,
                                               const float* __restrict__ bias,
                                               float* __restrict__ out,
                                               int n)
{
    __shared__ int sbs[BSEG + 1];
    __shared__ v4f s_scale[BSEG * 32];   // [seg][channel-quad]
    __shared__ v4f s_shift[BSEG * 32];

    if (threadIdx.x <= BSEG)
        sbs[threadIdx.x] = lower_bound_dev(bidx, n, (int)threadIdx.x);
    __syncthreads();

    for (int i = threadIdx.x; i < BSEG * CC; i += 256) {
        const int b = i >> 7;          // CC == 128
        const int c = i & (CC - 1);
        const float nn   = fmaxf((float)(sbs[b + 1] - sbs[b]), 1.0f);
        const float mean = sum[i] / nn;
        const float var  = fmaxf(sumsq[i] / nn - mean * mean, 0.0f);
        const float sc   = rsqrtf(var + EPSV) * w[c];
        reinterpret_cast<float*>(s_scale)[i] = sc;
        reinterpret_cast<float*>(s_shift)[i] = fmaf(-mean, sc, bias[c]);
    }
    __syncthreads();

    // Segment row-boundaries in registers for the (rare) boundary-tile path.
    int rb[BSEG - 1];
    #pragma unroll
    for (int i = 0; i < BSEG - 1; ++i) rb[i] = sbs[i + 1];

    const int total  = n * 32;                               // float4 count
    const int ntiles = (total + TILE_F4 - 1) / TILE_F4;
    const int tid    = (int)threadIdx.x;
    const int cq     = tid & 31;       // channel quad, tile-invariant
    const v4f* __restrict__ x4 = reinterpret_cast<const v4f*>(x);
    v4f* __restrict__ out4     = reinterpret_cast<v4f*>(out);

    for (int t = ntiles - 1 - (int)blockIdx.x; t >= 0; t -= (int)gridDim.x) {
        const int fbase = t * TILE_F4;
        const int fend  = min(fbase + TILE_F4, total);
        const int sA = bidx[fbase >> 5];
        const int sB = bidx[(fend - 1) >> 5];

        if (sA == sB) {
            const v4f sc = s_scale[sA * 32 + cq];
            const v4f sh = s_shift[sA * 32 + cq];
            if (fend == fbase + TILE_F4) {
                // Full uniform tile: unguarded, dense copy-shaped loop.
                const int f0 = fbase + tid;
                #pragma unroll
                for (int j = 0; j < TILE_F4 / 256; ++j) {
                    const size_t fi = (size_t)(f0 + j * 256);
                    const v4f a = x4[fi];
                    v4f o;
                    o.x = fmaf(a.x, sc.x, sh.x); o.y = fmaf(a.y, sc.y, sh.y);
                    o.z = fmaf(a.z, sc.z, sh.z); o.w = fmaf(a.w, sc.w, sh.w);
                    __builtin_nontemporal_store(o, out4 + fi);
                }
            } else {
                // Partial uniform tile (global tail tile only).
                for (int f = fbase + tid; f < fend; f += 256) {
                    const size_t fi = (size_t)f;
                    const v4f a = x4[fi];
                    v4f o;
                    o.x = fmaf(a.x, sc.x, sh.x); o.y = fmaf(a.y, sc.y, sh.y);
                    o.z = fmaf(a.z, sc.z, sh.z); o.w = fmaf(a.w, sc.w, sh.w);
                    __builtin_nontemporal_store(o, out4 + fi);
                }
            }
        } else {
            // Boundary tile (rare): seg via register compares; cq invariant.
            for (int f = fbase + tid; f < fend; f += 256) {
                const int r = f >> 5;
                int seg = 0;
                #pragma unroll
                for (int i = 0; i < BSEG - 1; ++i) seg += (r >= rb[i]);
                const v4f sc = s_scale[seg * 32 + cq];
                const v4f sh = s_shift[seg * 32 + cq];
                const size_t fi = (size_t)f;
                const v4f a = x4[fi];
                v4f o;
                o.x = fmaf(a.x, sc.x, sh.x); o.y = fmaf(a.y, sc.y, sh.y);
                o.z = fmaf(a.z, sc.z, sh.z); o.w = fmaf(a.w, sc.w, sh.w);
                __builtin_nontemporal_store(o, out4 + fi);
            }
        }
    }
}

// ---------------------------------------------------------------------------
extern "C" void kernel_launch(void* const* d_in, const int* in_sizes, int n_in,
                              void* d_out, int out_size, void* d_ws, size_t ws_size,
                              hipStream_t stream)
{
    const float* x    = (const float*)d_in[0];
    const int*   bidx = (const int*)d_in[1];
    const float* w    = (const float*)d_in[2];
    const float* bias = (const float*)d_in[3];
    float* out = (float*)d_out;
    const int n = in_sizes[1];   // number of rows (batch_idx length)

    // Workspace layout (floats): sum[B*C] | sumsq[B*C]
    float* ws    = (float*)d_ws;
    float* sum   = ws;
    float* sumsq = ws + BSEG * CC;

    // Zero the accumulators (ws is poisoned; must be replay-safe).
    (void)hipMemsetAsync(d_ws, 0, (size_t)(2 * BSEG * CC) * sizeof(float), stream);

    const int g1 = (n + ROWS_PER_BLOCK - 1) / ROWS_PER_BLOCK;
    ms_stats<<<g1, 256, 0, stream>>>(x, bidx, n, sum, sumsq);
    ms_norm<<<NORM_GRID, 256, 0, stream>>>(x, bidx, sum, sumsq, w, bias, out, n);
}

// Round 14
// 300.809 us; speedup vs baseline: 1.1035x; 1.1035x over previous
//
#include <hip/hip_runtime.h>

#define CC 128          // channels
#define BSEG 16         // segments
#define EPSV 1e-5f
#define ROWS_PER_BLOCK 512
#define NORM_GRID 2048
#define TILE_F4 4096    // float4s per tile = 128 rows = 64 KB (TILE_F4 % 256 == 0)

// Native clang vector (valid for __builtin_nontemporal_store, unlike HIP float4).
typedef float v4f __attribute__((ext_vector_type(4)));

// first index i in [0,n) with a[i] >= v   (a sorted ascending)
__device__ __forceinline__ int lower_bound_dev(const int* __restrict__ a, int n, int v)
{
    int lo = 0, hi = n;
    while (lo < hi) {
        const int mid = (lo + hi) >> 1;
        if (a[mid] < v) lo = mid + 1; else hi = mid;
    }
    return lo;
}

// ---------------------------------------------------------------------------
// Kernel 1: per-segment per-channel sum / sumsq (R10 exact: best measured).
// Block owns 512 contiguous rows (1953 blocks ~ 7.6/CU), FORWARD traversal
// leaves the tail of x freshest in L3 for the reverse-order normalize pass.
// 2-deep independent loads; uniform blocks LDS-reduce + 256 atomics;
// boundary blocks (<=15) flush-on-segment-change.
// (R13 showed 1024-row blocks + 4-deep loads REGRESS ~30us: don't re-try.)
// ---------------------------------------------------------------------------
__global__ __launch_bounds__(256) void ms_stats(const float* __restrict__ x,
                                                const int* __restrict__ bidx,
                                                int n,
                                                float* __restrict__ sum,
                                                float* __restrict__ sumsq)
{
    const int r0 = blockIdx.x * ROWS_PER_BLOCK;
    if (r0 >= n) return;
    const int rend = min(r0 + ROWS_PER_BLOCK, n);
    const int tq = threadIdx.x & 31;   // channel quad 0..31
    const int tr = threadIdx.x >> 5;   // row lane 0..7

    const int seg_first = bidx[r0];
    const int seg_last  = bidx[rend - 1];

    v4f s = {0.f, 0.f, 0.f, 0.f};
    v4f q = {0.f, 0.f, 0.f, 0.f};

    if (seg_first == seg_last) {
        int r = r0 + tr;
        for (; r + 8 < rend; r += 16) {
            const v4f a = *reinterpret_cast<const v4f*>(x + (size_t)r * CC + tq * 4);
            const v4f b = *reinterpret_cast<const v4f*>(x + (size_t)(r + 8) * CC + tq * 4);
            s += a; q += a * a;
            s += b; q += b * b;
        }
        if (r < rend) {
            const v4f a = *reinterpret_cast<const v4f*>(x + (size_t)r * CC + tq * 4);
            s += a; q += a * a;
        }
        __shared__ float red[8][8][32];
        red[tr][0][tq] = s.x; red[tr][1][tq] = s.y; red[tr][2][tq] = s.z; red[tr][3][tq] = s.w;
        red[tr][4][tq] = q.x; red[tr][5][tq] = q.y; red[tr][6][tq] = q.z; red[tr][7][tq] = q.w;
        __syncthreads();
        const int j = threadIdx.x >> 5;   // slot 0..7 (0-3 sum, 4-7 sumsq)
        float acc = 0.f;
        #pragma unroll
        for (int k = 0; k < 8; ++k) acc += red[k][j][tq];
        const int ch = tq * 4 + (j & 3);
        atomicAdd(((j < 4) ? sum : sumsq) + seg_first * CC + ch, acc);
    } else {
        int cur = -1;
        for (int r = r0 + tr; r < rend; r += 8) {
            const int seg = bidx[r];
            if (seg != cur) {
                if (cur >= 0) {
                    float* sd = sum   + cur * CC + tq * 4;
                    float* qd = sumsq + cur * CC + tq * 4;
                    atomicAdd(sd + 0, s.x); atomicAdd(sd + 1, s.y);
                    atomicAdd(sd + 2, s.z); atomicAdd(sd + 3, s.w);
                    atomicAdd(qd + 0, q.x); atomicAdd(qd + 1, q.y);
                    atomicAdd(qd + 2, q.z); atomicAdd(qd + 3, q.w);
                    s = (v4f){0.f, 0.f, 0.f, 0.f};
                    q = (v4f){0.f, 0.f, 0.f, 0.f};
                }
                cur = seg;
            }
            const v4f a = *reinterpret_cast<const v4f*>(x + (size_t)r * CC + tq * 4);
            s += a; q += a * a;
        }
        if (cur >= 0) {
            float* sd = sum   + cur * CC + tq * 4;
            float* qd = sumsq + cur * CC + tq * 4;
            atomicAdd(sd + 0, s.x); atomicAdd(sd + 1, s.y);
            atomicAdd(sd + 2, s.z); atomicAdd(sd + 3, s.w);
            atomicAdd(qd + 0, q.x); atomicAdd(qd + 1, q.y);
            atomicAdd(qd + 2, q.z); atomicAdd(qd + 3, q.w);
        }
    }
}

// ---------------------------------------------------------------------------
// Kernel 2: normalize (R10 exact: best measured, 302us total).
// Block-tile reverse sweep: 64KB tiles descending from the tail harvest the
// L3-resident tail left by ms_stats (measured FETCH 257MB of 512MB).
// Dense per-lane float4 I/O (pair-interleave caused 1.6x write amplification
// — R9). NT stores protect the L3 harvest (removing them costs +33us — R11).
// Uniform tiles (~99.8%) hold scale/shift in 2 registers; boundary tiles
// derive seg from register compares against binary-searched boundaries.
// ---------------------------------------------------------------------------
__global__ __launch_bounds__(256) void ms_norm(const float* __restrict__ x,
                                               const int* __restrict__ bidx,
                                               const float* __restrict__ sum,
                                               const float* __restrict__ sumsq,
                                               const float* __restrict__ w,
                                               const float* __restrict__ bias,
                                               float* __restrict__ out,
                                               int n)
{
    __shared__ int sbs[BSEG + 1];
    __shared__ v4f s_scale[BSEG * 32];   // [seg][channel-quad]
    __shared__ v4f s_shift[BSEG * 32];

    if (threadIdx.x <= BSEG)
        sbs[threadIdx.x] = lower_bound_dev(bidx, n, (int)threadIdx.x);
    __syncthreads();

    for (int i = threadIdx.x; i < BSEG * CC; i += 256) {
        const int b = i >> 7;          // CC == 128
        const int c = i & (CC - 1);
        const float nn   = fmaxf((float)(sbs[b + 1] - sbs[b]), 1.0f);
        const float mean = sum[i] / nn;
        const float var  = fmaxf(sumsq[i] / nn - mean * mean, 0.0f);
        const float sc   = rsqrtf(var + EPSV) * w[c];
        reinterpret_cast<float*>(s_scale)[i] = sc;
        reinterpret_cast<float*>(s_shift)[i] = fmaf(-mean, sc, bias[c]);
    }
    __syncthreads();

    // Segment row-boundaries in registers for the (rare) boundary-tile path.
    int rb[BSEG - 1];
    #pragma unroll
    for (int i = 0; i < BSEG - 1; ++i) rb[i] = sbs[i + 1];

    const int total  = n * 32;                               // float4 count
    const int ntiles = (total + TILE_F4 - 1) / TILE_F4;
    const int tid    = (int)threadIdx.x;
    const int cq     = tid & 31;       // channel quad, tile-invariant
    const v4f* __restrict__ x4 = reinterpret_cast<const v4f*>(x);
    v4f* __restrict__ out4     = reinterpret_cast<v4f*>(out);

    for (int t = ntiles - 1 - (int)blockIdx.x; t >= 0; t -= (int)gridDim.x) {
        const int fbase = t * TILE_F4;
        const int fend  = min(fbase + TILE_F4, total);
        const int sA = bidx[fbase >> 5];
        const int sB = bidx[(fend - 1) >> 5];

        if (sA == sB) {
            const v4f sc = s_scale[sA * 32 + cq];
            const v4f sh = s_shift[sA * 32 + cq];
            if (fend == fbase + TILE_F4) {
                // Full uniform tile: unguarded, dense copy-shaped loop.
                const int f0 = fbase + tid;
                #pragma unroll
                for (int j = 0; j < TILE_F4 / 256; ++j) {
                    const size_t fi = (size_t)(f0 + j * 256);
                    const v4f a = x4[fi];
                    v4f o;
                    o.x = fmaf(a.x, sc.x, sh.x); o.y = fmaf(a.y, sc.y, sh.y);
                    o.z = fmaf(a.z, sc.z, sh.z); o.w = fmaf(a.w, sc.w, sh.w);
                    __builtin_nontemporal_store(o, out4 + fi);
                }
            } else {
                // Partial uniform tile (global tail tile only).
                for (int f = fbase + tid; f < fend; f += 256) {
                    const size_t fi = (size_t)f;
                    const v4f a = x4[fi];
                    v4f o;
                    o.x = fmaf(a.x, sc.x, sh.x); o.y = fmaf(a.y, sc.y, sh.y);
                    o.z = fmaf(a.z, sc.z, sh.z); o.w = fmaf(a.w, sc.w, sh.w);
                    __builtin_nontemporal_store(o, out4 + fi);
                }
            }
        } else {
            // Boundary tile (rare): seg via register compares; cq invariant.
            for (int f = fbase + tid; f < fend; f += 256) {
                const int r = f >> 5;
                int seg = 0;
                #pragma unroll
                for (int i = 0; i < BSEG - 1; ++i) seg += (r >= rb[i]);
                const v4f sc = s_scale[seg * 32 + cq];
                const v4f sh = s_shift[seg * 32 + cq];
                const size_t fi = (size_t)f;
                const v4f a = x4[fi];
                v4f o;
                o.x = fmaf(a.x, sc.x, sh.x); o.y = fmaf(a.y, sc.y, sh.y);
                o.z = fmaf(a.z, sc.z, sh.z); o.w = fmaf(a.w, sc.w, sh.w);
                __builtin_nontemporal_store(o, out4 + fi);
            }
        }
    }
}

// ---------------------------------------------------------------------------
extern "C" void kernel_launch(void* const* d_in, const int* in_sizes, int n_in,
                              void* d_out, int out_size, void* d_ws, size_t ws_size,
                              hipStream_t stream)
{
    const float* x    = (const float*)d_in[0];
    const int*   bidx = (const int*)d_in[1];
    const float* w    = (const float*)d_in[2];
    const float* bias = (const float*)d_in[3];
    float* out = (float*)d_out;
    const int n = in_sizes[1];   // number of rows (batch_idx length)

    // Workspace layout (floats): sum[B*C] | sumsq[B*C]
    float* ws    = (float*)d_ws;
    float* sum   = ws;
    float* sumsq = ws + BSEG * CC;

    // Zero the accumulators (ws is poisoned; must be replay-safe).
    (void)hipMemsetAsync(d_ws, 0, (size_t)(2 * BSEG * CC) * sizeof(float), stream);

    const int g1 = (n + ROWS_PER_BLOCK - 1) / ROWS_PER_BLOCK;
    ms_stats<<<g1, 256, 0, stream>>>(x, bidx, n, sum, sumsq);
    ms_norm<<<NORM_GRID, 256, 0, stream>>>(x, bidx, sum, sumsq, w, bias, out, n);
}